// Round 1
// baseline (911.663 us; speedup 1.0000x reference)
//
#include <hip/hip_runtime.h>
#include <cstdint>
#include <cstddef>

#define CH 256      // all layers are 256-channel
#define BM 128
#define BN 64
#define BK 16

// ---------------- helpers ----------------

__device__ __forceinline__ int ld_idx(const void* p, long long i, int w64) {
    if (w64) return (int)((const long long*)p)[i];
    return ((const int*)p)[i];
}

__device__ __forceinline__ float gelu_f(float x) {
    // jax.nn.gelu default (approximate=True, tanh form)
    float x3 = x * x * x;
    float t = tanhf(0.7978845608028654f * (x + 0.044715f * x3));
    return 0.5f * x * (1.0f + t);
}

// ---------------- preprocessing ----------------

// Detect whether edge_index is int64 (little-endian: odd int32 words are the
// zero high-halves) or int32. Deterministic: pure function of input data.
__global__ void k_detect(const void* __restrict__ ei, int* __restrict__ flag, int E) {
    int l = threadIdx.x;  // 0..63
    long long k = ((long long)l * (long long)(E - 1)) / 63;  // 0..E-1
    int w = ((const int*)ei)[2 * k + 1];
    unsigned long long vote = __ballot(w == 0);
    if (l == 0) *flag = (vote == ~0ULL) ? 1 : 0;
}

__global__ void k_deg(const void* __restrict__ ei, const int* __restrict__ flag,
                      int* __restrict__ deg, int E) {
    int e = blockIdx.x * blockDim.x + threadIdx.x;
    if (e >= E) return;
    int w64 = *flag;
    int d = ld_idx(ei, (long long)E + e, w64);
    atomicAdd(&deg[d], 1);
}

__global__ void k_dis(const int* __restrict__ deg, float* __restrict__ dis, int N) {
    int n = blockIdx.x * blockDim.x + threadIdx.x;
    if (n >= N) return;
    // reference: deg includes self-loop -> indeg+1 >= 1, so branch never 0
    dis[n] = 1.0f / sqrtf((float)(deg[n] + 1));
}

// exclusive scan of deg -> rowptr (per-256 block), block totals -> partial
__global__ void k_scan_block(const int* __restrict__ deg, int* __restrict__ rowptr,
                             int* __restrict__ partial, int N) {
    __shared__ int s[256];
    int gid = blockIdx.x * 256 + threadIdx.x;
    int v = (gid < N) ? deg[gid] : 0;
    s[threadIdx.x] = v;
    __syncthreads();
    for (int off = 1; off < 256; off <<= 1) {
        int t = (threadIdx.x >= off) ? s[threadIdx.x - off] : 0;
        __syncthreads();
        s[threadIdx.x] += t;
        __syncthreads();
    }
    if (gid < N) rowptr[gid] = s[threadIdx.x] - v;   // exclusive within block
    if (threadIdx.x == 255) partial[blockIdx.x] = s[255];
}

__global__ void k_scan_partial(int* __restrict__ partial, int nb) {
    __shared__ int s[256];
    int i = threadIdx.x;
    int v = (i < nb) ? partial[i] : 0;
    s[i] = v;
    __syncthreads();
    for (int off = 1; off < 256; off <<= 1) {
        int t = (i >= off) ? s[i - off] : 0;
        __syncthreads();
        s[i] += t;
        __syncthreads();
    }
    if (i < nb) partial[i] = s[i] - v;  // exclusive across blocks
}

__global__ void k_add_off(int* __restrict__ rowptr, const int* __restrict__ partial,
                          int N, int E) {
    int gid = blockIdx.x * 256 + threadIdx.x;
    if (gid < N) rowptr[gid] += partial[blockIdx.x];
    if (gid == 0) rowptr[N] = E;
}

__global__ void k_scatter(const void* __restrict__ ei, const int* __restrict__ flag,
                          const float* __restrict__ dis, const int* __restrict__ rowptr,
                          int* __restrict__ cnt, int* __restrict__ ssrc,
                          float* __restrict__ snorm, int E) {
    int e = blockIdx.x * blockDim.x + threadIdx.x;
    if (e >= E) return;
    int w64 = *flag;
    int s = ld_idx(ei, e, w64);
    int d = ld_idx(ei, (long long)E + e, w64);
    int pos = rowptr[d] + atomicAdd(&cnt[d], 1);
    ssrc[pos] = s;
    snorm[pos] = dis[s] * dis[d];
}

// ---------------- dense transform: H = A @ W (fp32) ----------------
// A: M x 256, W: 256 x 256 row-major, H: M x 256

__global__ __launch_bounds__(256) void k_gemm(const float* __restrict__ A,
                                              const float* __restrict__ W,
                                              float* __restrict__ H, int M) {
    __shared__ float As[BK][BM + 1];
    __shared__ float Bs[BK][BN];
    int tx = threadIdx.x & 15, ty = threadIdx.x >> 4;
    int m0 = blockIdx.x * BM;
    int n0 = blockIdx.y * BN;
    float acc[8][4] = {};

    for (int k0 = 0; k0 < CH; k0 += BK) {
        #pragma unroll
        for (int i = 0; i < 8; i++) {
            int t = threadIdx.x + i * 256;
            int r = t >> 4;         // 0..127
            int c = t & 15;         // 0..15
            int row = m0 + r;
            As[c][r] = (row < M) ? A[(size_t)row * CH + k0 + c] : 0.f;
        }
        #pragma unroll
        for (int i = 0; i < 4; i++) {
            int t = threadIdx.x + i * 256;
            int r = t >> 6;         // 0..15
            int c = t & 63;         // 0..63
            Bs[r][c] = W[(size_t)(k0 + r) * CH + n0 + c];
        }
        __syncthreads();
        #pragma unroll
        for (int k = 0; k < BK; k++) {
            float a[8], b[4];
            #pragma unroll
            for (int i = 0; i < 8; i++) a[i] = As[k][ty * 8 + i];
            #pragma unroll
            for (int j = 0; j < 4; j++) b[j] = Bs[k][tx * 4 + j];
            #pragma unroll
            for (int i = 0; i < 8; i++)
                #pragma unroll
                for (int j = 0; j < 4; j++)
                    acc[i][j] += a[i] * b[j];
        }
        __syncthreads();
    }
    #pragma unroll
    for (int i = 0; i < 8; i++) {
        int row = m0 + ty * 8 + i;
        if (row < M) {
            float4 v = make_float4(acc[i][0], acc[i][1], acc[i][2], acc[i][3]);
            *(float4*)&H[(size_t)row * CH + n0 + (size_t)tx * 4] = v;
        }
    }
}

// ---------------- sparse aggregation (gather-CSR) ----------------
// out[n] = dis[n]^2 * H[n] + sum_{incoming e} snorm[e] * H[ssrc[e]]  (+bias, gelu?)
// one wave per node, 64 lanes x float4 = 256 channels

__global__ __launch_bounds__(256) void k_agg(const float* __restrict__ H,
                                             const float* __restrict__ dis,
                                             const int* __restrict__ rowptr,
                                             const int* __restrict__ ssrc,
                                             const float* __restrict__ snorm,
                                             const float* __restrict__ bias,
                                             float* __restrict__ out, int N, int do_gelu) {
    int node = blockIdx.x * 4 + threadIdx.y;
    if (node >= N) return;
    int lane = threadIdx.x;  // 0..63
    float d = dis[node];
    float w = d * d;
    float4 hv = ((const float4*)(H + (size_t)node * CH))[lane];
    float4 acc;
    acc.x = w * hv.x; acc.y = w * hv.y; acc.z = w * hv.z; acc.w = w * hv.w;
    int s = rowptr[node], e = rowptr[node + 1];
    for (int j = s; j < e; j++) {
        int src = ssrc[j];
        float wn = snorm[j];
        float4 v = ((const float4*)(H + (size_t)src * CH))[lane];
        acc.x += wn * v.x; acc.y += wn * v.y; acc.z += wn * v.z; acc.w += wn * v.w;
    }
    float4 b = ((const float4*)bias)[lane];
    acc.x += b.x; acc.y += b.y; acc.z += b.z; acc.w += b.w;
    if (do_gelu) {
        acc.x = gelu_f(acc.x); acc.y = gelu_f(acc.y);
        acc.z = gelu_f(acc.z); acc.w = gelu_f(acc.w);
    }
    ((float4*)(out + (size_t)node * CH))[lane] = acc;
}

// ---------------- launcher ----------------

extern "C" void kernel_launch(void* const* d_in, const int* in_sizes, int n_in,
                              void* d_out, int out_size, void* d_ws, size_t ws_size,
                              hipStream_t stream) {
    const float* x  = (const float*)d_in[0];
    const void*  ei = d_in[1];
    // d_in[2] = batch (unused)
    const float* W1 = (const float*)d_in[3]; const float* b1 = (const float*)d_in[4];
    const float* W2 = (const float*)d_in[5]; const float* b2 = (const float*)d_in[6];
    const float* W3 = (const float*)d_in[7]; const float* b3 = (const float*)d_in[8];

    int N = in_sizes[0] / CH;
    int E = in_sizes[1] / 2;
    float* out = (float*)d_out;

    // workspace carve-up (16B aligned slabs)
    char* ws = (char*)d_ws;
    auto take = [&](size_t bytes) {
        char* p = ws;
        ws += (bytes + 15) & ~(size_t)15;
        return p;
    };
    float* H      = (float*)take((size_t)N * CH * sizeof(float));
    int*   deg    = (int*)  take((size_t)N * sizeof(int));
    float* dis    = (float*)take((size_t)N * sizeof(float));
    int*   rowptr = (int*)  take((size_t)(N + 1) * sizeof(int));
    int*   cnt    = (int*)  take((size_t)N * sizeof(int));
    int*   part   = (int*)  take(4096);
    int*   flag   = (int*)  take(16);
    int*   ssrc   = (int*)  take((size_t)E * sizeof(int));
    float* snorm  = (float*)take((size_t)E * sizeof(float));

    hipMemsetAsync(deg, 0, (size_t)N * sizeof(int), stream);
    hipMemsetAsync(cnt, 0, (size_t)N * sizeof(int), stream);

    int eb = (E + 255) / 256;
    int nb = (N + 255) / 256;

    k_detect<<<1, 64, 0, stream>>>(ei, flag, E);
    k_deg<<<eb, 256, 0, stream>>>(ei, flag, deg, E);
    k_dis<<<nb, 256, 0, stream>>>(deg, dis, N);
    k_scan_block<<<nb, 256, 0, stream>>>(deg, rowptr, part, N);
    k_scan_partial<<<1, 256, 0, stream>>>(part, nb);
    k_add_off<<<nb, 256, 0, stream>>>(rowptr, part, N, E);
    k_scatter<<<eb, 256, 0, stream>>>(ei, flag, dis, rowptr, cnt, ssrc, snorm, E);

    dim3 ggrid((N + BM - 1) / BM, CH / BN);
    dim3 agrid((N + 3) / 4);
    dim3 ablock(64, 4);

    // layer 1: H = x@W1 ; out = agg(H)+b1 ; gelu
    k_gemm<<<ggrid, 256, 0, stream>>>(x, W1, H, N);
    k_agg<<<agrid, ablock, 0, stream>>>(H, dis, rowptr, ssrc, snorm, b1, out, N, 1);
    // layer 2
    k_gemm<<<ggrid, 256, 0, stream>>>(out, W2, H, N);
    k_agg<<<agrid, ablock, 0, stream>>>(H, dis, rowptr, ssrc, snorm, b2, out, N, 1);
    // layer 3 (no gelu)
    k_gemm<<<ggrid, 256, 0, stream>>>(out, W3, H, N);
    k_agg<<<agrid, ablock, 0, stream>>>(H, dis, rowptr, ssrc, snorm, b3, out, N, 0);
}

// Round 3
// 594.866 us; speedup vs baseline: 1.5326x; 1.5326x over previous
//
#include <hip/hip_runtime.h>
#include <cstdint>
#include <cstddef>

#define CH 256      // all layers are 256-channel

typedef _Float16 f16x8 __attribute__((ext_vector_type(8)));
typedef float f32x4 __attribute__((ext_vector_type(4)));

#define GLOB(x) ((const __attribute__((address_space(1))) void*)(x))
#define LDSP(x) ((__attribute__((address_space(3))) void*)(x))

// ---------------- helpers ----------------

__device__ __forceinline__ int ld_idx(const void* p, long long i, int w64) {
    if (w64) return (int)((const long long*)p)[i];
    return ((const int*)p)[i];
}

__device__ __forceinline__ float gelu_f(float x) {
    // jax.nn.gelu default (approximate=True, tanh form)
    float x3 = x * x * x;
    float t = tanhf(0.7978845608028654f * (x + 0.044715f * x3));
    return 0.5f * x * (1.0f + t);
}

// ---------------- preprocessing ----------------

__global__ void k_detect(const void* __restrict__ ei, int* __restrict__ flag, int E) {
    int l = threadIdx.x;  // 0..63
    long long k = ((long long)l * (long long)(E - 1)) / 63;  // 0..E-1
    int w = ((const int*)ei)[2 * k + 1];
    unsigned long long vote = __ballot(w == 0);
    if (l == 0) *flag = (vote == ~0ULL) ? 1 : 0;
}

__global__ void k_deg(const void* __restrict__ ei, const int* __restrict__ flag,
                      int* __restrict__ deg, int E) {
    int e = blockIdx.x * blockDim.x + threadIdx.x;
    if (e >= E) return;
    int w64 = *flag;
    int d = ld_idx(ei, (long long)E + e, w64);
    atomicAdd(&deg[d], 1);
}

__global__ void k_dis(const int* __restrict__ deg, float* __restrict__ dis, int N) {
    int n = blockIdx.x * blockDim.x + threadIdx.x;
    if (n >= N) return;
    dis[n] = 1.0f / sqrtf((float)(deg[n] + 1));
}

__global__ void k_scan_block(const int* __restrict__ deg, int* __restrict__ rowptr,
                             int* __restrict__ partial, int N) {
    __shared__ int s[256];
    int gid = blockIdx.x * 256 + threadIdx.x;
    int v = (gid < N) ? deg[gid] : 0;
    s[threadIdx.x] = v;
    __syncthreads();
    for (int off = 1; off < 256; off <<= 1) {
        int t = (threadIdx.x >= off) ? s[threadIdx.x - off] : 0;
        __syncthreads();
        s[threadIdx.x] += t;
        __syncthreads();
    }
    if (gid < N) rowptr[gid] = s[threadIdx.x] - v;
    if (threadIdx.x == 255) partial[blockIdx.x] = s[255];
}

__global__ void k_scan_partial(int* __restrict__ partial, int nb) {
    __shared__ int s[256];
    int i = threadIdx.x;
    int v = (i < nb) ? partial[i] : 0;
    s[i] = v;
    __syncthreads();
    for (int off = 1; off < 256; off <<= 1) {
        int t = (i >= off) ? s[i - off] : 0;
        __syncthreads();
        s[i] += t;
        __syncthreads();
    }
    if (i < nb) partial[i] = s[i] - v;
}

__global__ void k_add_off(int* __restrict__ rowptr, const int* __restrict__ partial,
                          int N, int E) {
    int gid = blockIdx.x * 256 + threadIdx.x;
    if (gid < N) rowptr[gid] += partial[blockIdx.x];
    if (gid == 0) rowptr[N] = E;
}

__global__ void k_scatter(const void* __restrict__ ei, const int* __restrict__ flag,
                          const float* __restrict__ dis, const int* __restrict__ rowptr,
                          int* __restrict__ cnt, int* __restrict__ ssrc,
                          float* __restrict__ snorm, int E) {
    int e = blockIdx.x * blockDim.x + threadIdx.x;
    if (e >= E) return;
    int w64 = *flag;
    int s = ld_idx(ei, e, w64);
    int d = ld_idx(ei, (long long)E + e, w64);
    int pos = rowptr[d] + atomicAdd(&cnt[d], 1);
    ssrc[pos] = s;
    snorm[pos] = dis[s] * dis[d];
}

// ---------------- weight split: W[k][c] fp32 -> Wt hi/lo fp16 [c][k] ----------------

__global__ void k_split_w(const float* __restrict__ W, _Float16* __restrict__ Wh,
                          _Float16* __restrict__ Wl) {
    int k = threadIdx.x;   // 0..255
    int c = blockIdx.x;    // 0..255
    float v = W[k * CH + c];
    _Float16 h = (_Float16)v;
    Wh[c * CH + k] = h;
    Wl[c * CH + k] = (_Float16)(v - (float)h);
}

// ---------------- fp16x2 split GEMM via MFMA ----------------
// H[M,256] = A[M,256] @ W[256,256], with W pre-split+transposed (Bh/Bl = [c][k]).
// A staged fp32 to LDS, split to f16 hi/lo in registers.
// Block: 128x128 output, 4 waves of 64x64, MFMA 16x16x32_f16, K-step 32.

#define GM 128
#define GN 128
#define GK 32

__global__ __launch_bounds__(256, 2)
void k_gemm16(const float* __restrict__ A, const _Float16* __restrict__ Bh,
              const _Float16* __restrict__ Bl, float* __restrict__ H, int M) {
    __shared__ float    lA[2][GM * GK];       // 16 KB per buf, chunk-swizzled
    __shared__ _Float16 lB[2][2][GN * GK];    // 8 KB per plane per buf, chunk-swizzled

    const int tid  = threadIdx.x;
    const int lane = tid & 63;
    const int wid  = tid >> 6;
    const int m0   = blockIdx.x * GM;
    const int n0   = blockIdx.y * GN;
    const int wm   = wid >> 1, wn = wid & 1;
    const int r15  = lane & 15, kg = lane >> 4;

    // stage one K-step tile into buffer `buf`:
    // A = 1024 chunks (16 calls), Bh = 512 (8 calls), Bl = 512 (8 calls) -> 32 calls, 8/wave
    auto stage = [&](int buf, int k0) {
        #pragma unroll
        for (int c = 0; c < 8; c++) {
            int call = wid * 8 + c;                 // wave-uniform 0..31
            if (call < 16) {                        // A fp32: 128 rows x 8 chunks(16B)
                int L = call * 64 + lane;           // linear chunk 0..1023
                int row = L >> 3, ch = L & 7;
                int gr = m0 + row; gr = (gr < M) ? gr : (M - 1);
                const float* g = A + (size_t)gr * CH + k0 + ((ch ^ (row & 7)) << 2);
                __builtin_amdgcn_global_load_lds(GLOB(g), LDSP(&lA[buf][call * 256]), 16, 0, 0);
            } else if (call < 24) {                 // B hi: 128 rows x 4 chunks(16B)
                int cc = call - 16;
                int L = cc * 64 + lane;             // 0..511
                int row = L >> 2, ch = L & 3;
                const _Float16* g = Bh + (size_t)(n0 + row) * CH + k0 + ((ch ^ ((row >> 1) & 3)) << 3);
                __builtin_amdgcn_global_load_lds(GLOB(g), LDSP(&lB[buf][0][cc * 512]), 16, 0, 0);
            } else {                                // B lo
                int cc = call - 24;
                int L = cc * 64 + lane;
                int row = L >> 2, ch = L & 3;
                const _Float16* g = Bl + (size_t)(n0 + row) * CH + k0 + ((ch ^ ((row >> 1) & 3)) << 3);
                __builtin_amdgcn_global_load_lds(GLOB(g), LDSP(&lB[buf][1][cc * 512]), 16, 0, 0);
            }
        }
    };

    f32x4 acc[4][4];
    #pragma unroll
    for (int i = 0; i < 4; i++)
        #pragma unroll
        for (int n = 0; n < 4; n++)
            acc[i][n] = (f32x4){0.f, 0.f, 0.f, 0.f};

    stage(0, 0);
    __syncthreads();

    for (int ks = 0; ks < 8; ks++) {
        int cur = ks & 1;
        if (ks < 7) stage(cur ^ 1, (ks + 1) * GK);   // overlap with compute below

        f16x8 ah[4], al[4], bh[4], bl[4];
        #pragma unroll
        for (int i = 0; i < 4; i++) {
            int R  = wm * 64 + i * 16 + r15;
            int p0 = (2 * kg) ^ (R & 7);
            const f32x4* base = (const f32x4*)&lA[cur][R * GK];
            f32x4 va = base[p0];          // logical chunk 2kg   (k = 8kg..8kg+3)
            f32x4 vb = base[p0 ^ 1];      // logical chunk 2kg+1 (k = 8kg+4..8kg+7)
            #pragma unroll
            for (int j = 0; j < 4; j++) {
                float v = va[j];
                _Float16 h = (_Float16)v;
                ah[i][j] = h;
                al[i][j] = (_Float16)(v - (float)h);
            }
            #pragma unroll
            for (int j = 0; j < 4; j++) {
                float v = vb[j];
                _Float16 h = (_Float16)v;
                ah[i][4 + j] = h;
                al[i][4 + j] = (_Float16)(v - (float)h);
            }
        }
        #pragma unroll
        for (int n = 0; n < 4; n++) {
            int C = wn * 64 + n * 16 + r15;
            int p = kg ^ ((C >> 1) & 3);
            bh[n] = *(const f16x8*)&lB[cur][0][C * GK + p * 8];
            bl[n] = *(const f16x8*)&lB[cur][1][C * GK + p * 8];
        }
        #pragma unroll
        for (int i = 0; i < 4; i++)
            #pragma unroll
            for (int n = 0; n < 4; n++) {
                acc[i][n] = __builtin_amdgcn_mfma_f32_16x16x32_f16(ah[i], bh[n], acc[i][n], 0, 0, 0);
                acc[i][n] = __builtin_amdgcn_mfma_f32_16x16x32_f16(ah[i], bl[n], acc[i][n], 0, 0, 0);
                acc[i][n] = __builtin_amdgcn_mfma_f32_16x16x32_f16(al[i], bh[n], acc[i][n], 0, 0, 0);
            }
        __syncthreads();
    }

    // epilogue: C/D layout col=lane&15, row=(lane>>4)*4+reg
    #pragma unroll
    for (int i = 0; i < 4; i++) {
        int row_base = m0 + wm * 64 + i * 16 + kg * 4;
        #pragma unroll
        for (int n = 0; n < 4; n++) {
            int col = n0 + wn * 64 + n * 16 + r15;
            #pragma unroll
            for (int r = 0; r < 4; r++) {
                int row = row_base + r;
                if (row < M) H[(size_t)row * CH + col] = acc[i][n][r];
            }
        }
    }
}

// ---------------- sparse aggregation (gather-CSR) ----------------

__global__ __launch_bounds__(256) void k_agg(const float* __restrict__ H,
                                             const float* __restrict__ dis,
                                             const int* __restrict__ rowptr,
                                             const int* __restrict__ ssrc,
                                             const float* __restrict__ snorm,
                                             const float* __restrict__ bias,
                                             float* __restrict__ out, int N, int do_gelu) {
    int node = blockIdx.x * 4 + threadIdx.y;
    if (node >= N) return;
    int lane = threadIdx.x;  // 0..63
    float d = dis[node];
    float w = d * d;
    float4 hv = ((const float4*)(H + (size_t)node * CH))[lane];
    float4 acc;
    acc.x = w * hv.x; acc.y = w * hv.y; acc.z = w * hv.z; acc.w = w * hv.w;
    int s = rowptr[node], e = rowptr[node + 1];
    for (int j = s; j < e; j++) {
        int src = ssrc[j];
        float wn = snorm[j];
        float4 v = ((const float4*)(H + (size_t)src * CH))[lane];
        acc.x += wn * v.x; acc.y += wn * v.y; acc.z += wn * v.z; acc.w += wn * v.w;
    }
    float4 b = ((const float4*)bias)[lane];
    acc.x += b.x; acc.y += b.y; acc.z += b.z; acc.w += b.w;
    if (do_gelu) {
        acc.x = gelu_f(acc.x); acc.y = gelu_f(acc.y);
        acc.z = gelu_f(acc.z); acc.w = gelu_f(acc.w);
    }
    ((float4*)(out + (size_t)node * CH))[lane] = acc;
}

// ---------------- launcher ----------------

extern "C" void kernel_launch(void* const* d_in, const int* in_sizes, int n_in,
                              void* d_out, int out_size, void* d_ws, size_t ws_size,
                              hipStream_t stream) {
    const float* x  = (const float*)d_in[0];
    const void*  ei = d_in[1];
    const float* W1 = (const float*)d_in[3]; const float* b1 = (const float*)d_in[4];
    const float* W2 = (const float*)d_in[5]; const float* b2 = (const float*)d_in[6];
    const float* W3 = (const float*)d_in[7]; const float* b3 = (const float*)d_in[8];

    int N = in_sizes[0] / CH;
    int E = in_sizes[1] / 2;
    float* out = (float*)d_out;

    char* ws = (char*)d_ws;
    auto take = [&](size_t bytes) {
        char* p = ws;
        ws += (bytes + 15) & ~(size_t)15;
        return p;
    };
    float*    H      = (float*)   take((size_t)N * CH * sizeof(float));
    int*      deg    = (int*)     take((size_t)N * sizeof(int));
    float*    dis    = (float*)   take((size_t)N * sizeof(float));
    int*      rowptr = (int*)     take((size_t)(N + 1) * sizeof(int));
    int*      cnt    = (int*)     take((size_t)N * sizeof(int));
    int*      part   = (int*)     take(4096);
    int*      flag   = (int*)     take(16);
    int*      ssrc   = (int*)     take((size_t)E * sizeof(int));
    float*    snorm  = (float*)   take((size_t)E * sizeof(float));
    _Float16* Wh1    = (_Float16*)take((size_t)CH * CH * 2);
    _Float16* Wl1    = (_Float16*)take((size_t)CH * CH * 2);
    _Float16* Wh2    = (_Float16*)take((size_t)CH * CH * 2);
    _Float16* Wl2    = (_Float16*)take((size_t)CH * CH * 2);
    _Float16* Wh3    = (_Float16*)take((size_t)CH * CH * 2);
    _Float16* Wl3    = (_Float16*)take((size_t)CH * CH * 2);

    hipMemsetAsync(deg, 0, (size_t)N * sizeof(int), stream);
    hipMemsetAsync(cnt, 0, (size_t)N * sizeof(int), stream);

    int eb = (E + 255) / 256;
    int nb = (N + 255) / 256;

    k_detect<<<1, 64, 0, stream>>>(ei, flag, E);
    k_deg<<<eb, 256, 0, stream>>>(ei, flag, deg, E);
    k_dis<<<nb, 256, 0, stream>>>(deg, dis, N);
    k_scan_block<<<nb, 256, 0, stream>>>(deg, rowptr, part, N);
    k_scan_partial<<<1, 256, 0, stream>>>(part, nb);
    k_add_off<<<nb, 256, 0, stream>>>(rowptr, part, N, E);
    k_scatter<<<eb, 256, 0, stream>>>(ei, flag, dis, rowptr, cnt, ssrc, snorm, E);

    k_split_w<<<CH, CH, 0, stream>>>(W1, Wh1, Wl1);
    k_split_w<<<CH, CH, 0, stream>>>(W2, Wh2, Wl2);
    k_split_w<<<CH, CH, 0, stream>>>(W3, Wh3, Wl3);

    dim3 ggrid((N + GM - 1) / GM, CH / GN);
    dim3 agrid((N + 3) / 4);
    dim3 ablock(64, 4);

    // layer 1
    k_gemm16<<<ggrid, 256, 0, stream>>>(x, Wh1, Wl1, H, N);
    k_agg<<<agrid, ablock, 0, stream>>>(H, dis, rowptr, ssrc, snorm, b1, out, N, 1);
    // layer 2
    k_gemm16<<<ggrid, 256, 0, stream>>>(out, Wh2, Wl2, H, N);
    k_agg<<<agrid, ablock, 0, stream>>>(H, dis, rowptr, ssrc, snorm, b2, out, N, 1);
    // layer 3 (no gelu)
    k_gemm16<<<ggrid, 256, 0, stream>>>(out, Wh3, Wl3, H, N);
    k_agg<<<agrid, ablock, 0, stream>>>(H, dis, rowptr, ssrc, snorm, b3, out, N, 0);
}

// Round 4
// 586.136 us; speedup vs baseline: 1.5554x; 1.0149x over previous
//
#include <hip/hip_runtime.h>
#include <cstdint>
#include <cstddef>

#define CH 256      // all layers are 256-channel

typedef _Float16 f16x8 __attribute__((ext_vector_type(8)));
typedef float f32x4 __attribute__((ext_vector_type(4)));

#define GLOB(x) ((const __attribute__((address_space(1))) void*)(x))
#define LDSP(x) ((__attribute__((address_space(3))) void*)(x))

// ---------------- helpers ----------------

__device__ __forceinline__ int ld_idx(const void* p, long long i, int w64) {
    if (w64) return (int)((const long long*)p)[i];
    return ((const int*)p)[i];
}

__device__ __forceinline__ float gelu_f(float x) {
    // jax.nn.gelu default (approximate=True, tanh form)
    float x3 = x * x * x;
    float t = tanhf(0.7978845608028654f * (x + 0.044715f * x3));
    return 0.5f * x * (1.0f + t);
}

// ---------------- preprocessing ----------------

__global__ void k_detect(const void* __restrict__ ei, int* __restrict__ flag, int E) {
    int l = threadIdx.x;  // 0..63
    long long k = ((long long)l * (long long)(E - 1)) / 63;  // 0..E-1
    int w = ((const int*)ei)[2 * k + 1];
    unsigned long long vote = __ballot(w == 0);
    if (l == 0) *flag = (vote == ~0ULL) ? 1 : 0;
}

__global__ void k_deg(const void* __restrict__ ei, const int* __restrict__ flag,
                      int* __restrict__ deg, int E) {
    int e = blockIdx.x * blockDim.x + threadIdx.x;
    if (e >= E) return;
    int w64 = *flag;
    int d = ld_idx(ei, (long long)E + e, w64);
    atomicAdd(&deg[d], 1);
}

__global__ void k_dis(const int* __restrict__ deg, float* __restrict__ dis, int N) {
    int n = blockIdx.x * blockDim.x + threadIdx.x;
    if (n >= N) return;
    dis[n] = 1.0f / sqrtf((float)(deg[n] + 1));
}

__global__ void k_scan_block(const int* __restrict__ deg, int* __restrict__ rowptr,
                             int* __restrict__ partial, int N) {
    __shared__ int s[256];
    int gid = blockIdx.x * 256 + threadIdx.x;
    int v = (gid < N) ? deg[gid] : 0;
    s[threadIdx.x] = v;
    __syncthreads();
    for (int off = 1; off < 256; off <<= 1) {
        int t = (threadIdx.x >= off) ? s[threadIdx.x - off] : 0;
        __syncthreads();
        s[threadIdx.x] += t;
        __syncthreads();
    }
    if (gid < N) rowptr[gid] = s[threadIdx.x] - v;
    if (threadIdx.x == 255) partial[blockIdx.x] = s[255];
}

__global__ void k_scan_partial(int* __restrict__ partial, int nb) {
    __shared__ int s[256];
    int i = threadIdx.x;
    int v = (i < nb) ? partial[i] : 0;
    s[i] = v;
    __syncthreads();
    for (int off = 1; off < 256; off <<= 1) {
        int t = (i >= off) ? s[i - off] : 0;
        __syncthreads();
        s[i] += t;
        __syncthreads();
    }
    if (i < nb) partial[i] = s[i] - v;
}

__global__ void k_add_off(int* __restrict__ rowptr, const int* __restrict__ partial,
                          int N, int E) {
    int gid = blockIdx.x * 256 + threadIdx.x;
    if (gid < N) rowptr[gid] += partial[blockIdx.x];
    if (gid == 0) rowptr[N] = E;
}

__global__ void k_scatter(const void* __restrict__ ei, const int* __restrict__ flag,
                          const float* __restrict__ dis, const int* __restrict__ rowptr,
                          int* __restrict__ cnt, int2* __restrict__ epack, int E) {
    int e = blockIdx.x * blockDim.x + threadIdx.x;
    if (e >= E) return;
    int w64 = *flag;
    int s = ld_idx(ei, e, w64);
    int d = ld_idx(ei, (long long)E + e, w64);
    int pos = rowptr[d] + atomicAdd(&cnt[d], 1);
    epack[pos] = make_int2(s, __float_as_int(dis[s] * dis[d]));
}

// ---------------- weight split: W[k][c] fp32 -> Wt hi/lo fp16 [c][k] ----------------

__global__ void k_split_w(const float* __restrict__ W, _Float16* __restrict__ Wh,
                          _Float16* __restrict__ Wl) {
    int k = threadIdx.x;   // 0..255
    int c = blockIdx.x;    // 0..255
    float v = W[k * CH + c];
    _Float16 h = (_Float16)v;
    Wh[c * CH + k] = h;
    Wl[c * CH + k] = (_Float16)(v - (float)h);
}

// ---------------- fp16x2 split GEMM via MFMA ----------------
// H[M,256] = A[M,256] @ W[256,256], with W pre-split+transposed (Bh/Bl = [c][k]).
// A staged fp32 to LDS, split to f16 hi/lo in registers.
// Block: 128x128 output, 4 waves of 64x64, MFMA 16x16x32_f16, K-step 32.

#define GM 128
#define GN 128
#define GK 32

__global__ __launch_bounds__(256, 2)
void k_gemm16(const float* __restrict__ A, const _Float16* __restrict__ Bh,
              const _Float16* __restrict__ Bl, float* __restrict__ H, int M) {
    __shared__ float    lA[2][GM * GK];       // 16 KB per buf, chunk-swizzled
    __shared__ _Float16 lB[2][2][GN * GK];    // 8 KB per plane per buf, chunk-swizzled

    const int tid  = threadIdx.x;
    const int lane = tid & 63;
    const int wid  = tid >> 6;
    const int m0   = blockIdx.x * GM;
    const int n0   = blockIdx.y * GN;
    const int wm   = wid >> 1, wn = wid & 1;
    const int r15  = lane & 15, kg = lane >> 4;

    // stage one K-step tile into buffer `buf`:
    // A = 1024 chunks (16 calls), Bh = 512 (8 calls), Bl = 512 (8 calls) -> 32 calls, 8/wave
    auto stage = [&](int buf, int k0) {
        #pragma unroll
        for (int c = 0; c < 8; c++) {
            int call = wid * 8 + c;                 // wave-uniform 0..31
            if (call < 16) {                        // A fp32: 128 rows x 8 chunks(16B)
                int L = call * 64 + lane;           // linear chunk 0..1023
                int row = L >> 3, ch = L & 7;
                int gr = m0 + row; gr = (gr < M) ? gr : (M - 1);
                const float* g = A + (size_t)gr * CH + k0 + ((ch ^ (row & 7)) << 2);
                __builtin_amdgcn_global_load_lds(GLOB(g), LDSP(&lA[buf][call * 256]), 16, 0, 0);
            } else if (call < 24) {                 // B hi: 128 rows x 4 chunks(16B)
                int cc = call - 16;
                int L = cc * 64 + lane;             // 0..511
                int row = L >> 2, ch = L & 3;
                const _Float16* g = Bh + (size_t)(n0 + row) * CH + k0 + ((ch ^ ((row >> 1) & 3)) << 3);
                __builtin_amdgcn_global_load_lds(GLOB(g), LDSP(&lB[buf][0][cc * 512]), 16, 0, 0);
            } else {                                // B lo
                int cc = call - 24;
                int L = cc * 64 + lane;
                int row = L >> 2, ch = L & 3;
                const _Float16* g = Bl + (size_t)(n0 + row) * CH + k0 + ((ch ^ ((row >> 1) & 3)) << 3);
                __builtin_amdgcn_global_load_lds(GLOB(g), LDSP(&lB[buf][1][cc * 512]), 16, 0, 0);
            }
        }
    };

    f32x4 acc[4][4];
    #pragma unroll
    for (int i = 0; i < 4; i++)
        #pragma unroll
        for (int n = 0; n < 4; n++)
            acc[i][n] = (f32x4){0.f, 0.f, 0.f, 0.f};

    stage(0, 0);
    __syncthreads();

    for (int ks = 0; ks < 8; ks++) {
        int cur = ks & 1;
        if (ks < 7) stage(cur ^ 1, (ks + 1) * GK);   // overlap with compute below

        f16x8 ah[4], al[4], bh[4], bl[4];
        #pragma unroll
        for (int i = 0; i < 4; i++) {
            int R  = wm * 64 + i * 16 + r15;
            int p0 = (2 * kg) ^ (R & 7);
            const f32x4* base = (const f32x4*)&lA[cur][R * GK];
            f32x4 va = base[p0];          // logical chunk 2kg   (k = 8kg..8kg+3)
            f32x4 vb = base[p0 ^ 1];      // logical chunk 2kg+1 (k = 8kg+4..8kg+7)
            #pragma unroll
            for (int j = 0; j < 4; j++) {
                float v = va[j];
                _Float16 h = (_Float16)v;
                ah[i][j] = h;
                al[i][j] = (_Float16)(v - (float)h);
            }
            #pragma unroll
            for (int j = 0; j < 4; j++) {
                float v = vb[j];
                _Float16 h = (_Float16)v;
                ah[i][4 + j] = h;
                al[i][4 + j] = (_Float16)(v - (float)h);
            }
        }
        #pragma unroll
        for (int n = 0; n < 4; n++) {
            int C = wn * 64 + n * 16 + r15;
            int p = kg ^ ((C >> 1) & 3);
            bh[n] = *(const f16x8*)&lB[cur][0][C * GK + p * 8];
            bl[n] = *(const f16x8*)&lB[cur][1][C * GK + p * 8];
        }
        #pragma unroll
        for (int i = 0; i < 4; i++)
            #pragma unroll
            for (int n = 0; n < 4; n++) {
                acc[i][n] = __builtin_amdgcn_mfma_f32_16x16x32_f16(ah[i], bh[n], acc[i][n], 0, 0, 0);
                acc[i][n] = __builtin_amdgcn_mfma_f32_16x16x32_f16(ah[i], bl[n], acc[i][n], 0, 0, 0);
                acc[i][n] = __builtin_amdgcn_mfma_f32_16x16x32_f16(al[i], bh[n], acc[i][n], 0, 0, 0);
            }
        __syncthreads();
    }

    // epilogue: C/D layout col=lane&15, row=(lane>>4)*4+reg
    #pragma unroll
    for (int i = 0; i < 4; i++) {
        int row_base = m0 + wm * 64 + i * 16 + kg * 4;
        #pragma unroll
        for (int n = 0; n < 4; n++) {
            int col = n0 + wn * 64 + n * 16 + r15;
            #pragma unroll
            for (int r = 0; r < 4; r++) {
                int row = row_base + r;
                if (row < M) H[(size_t)row * CH + col] = acc[i][n][r];
            }
        }
    }
}

// ---------------- sparse aggregation (gather-CSR, 8-deep MLP) ----------------
// out[n] = dis[n]^2*H[n] + sum_e norm_e * H[src_e] (+bias, gelu?)
// one wave per node; edge loop unrolled 8x/4x for independent in-flight gathers

__global__ __launch_bounds__(256) void k_agg(const float* __restrict__ H,
                                             const float* __restrict__ dis,
                                             const int* __restrict__ rowptr,
                                             const int2* __restrict__ epack,
                                             const float* __restrict__ bias,
                                             float* __restrict__ out, int N, int do_gelu) {
    int node = blockIdx.x * 4 + threadIdx.y;
    if (node >= N) return;
    int lane = threadIdx.x;  // 0..63
    float d = dis[node];
    float w = d * d;
    float4 hv = ((const float4*)(H + (size_t)node * CH))[lane];
    float ax = w * hv.x, ay = w * hv.y, az = w * hv.z, aw = w * hv.w;
    int s = rowptr[node], e = rowptr[node + 1];
    int j = s;
    for (; j + 8 <= e; j += 8) {
        int2 p[8];
        #pragma unroll
        for (int t = 0; t < 8; t++) p[t] = epack[j + t];
        float4 v[8];
        #pragma unroll
        for (int t = 0; t < 8; t++)
            v[t] = ((const float4*)(H + (size_t)p[t].x * CH))[lane];
        #pragma unroll
        for (int t = 0; t < 8; t++) {
            float wn = __int_as_float(p[t].y);
            ax += wn * v[t].x; ay += wn * v[t].y; az += wn * v[t].z; aw += wn * v[t].w;
        }
    }
    for (; j + 4 <= e; j += 4) {
        int2 p[4];
        #pragma unroll
        for (int t = 0; t < 4; t++) p[t] = epack[j + t];
        float4 v[4];
        #pragma unroll
        for (int t = 0; t < 4; t++)
            v[t] = ((const float4*)(H + (size_t)p[t].x * CH))[lane];
        #pragma unroll
        for (int t = 0; t < 4; t++) {
            float wn = __int_as_float(p[t].y);
            ax += wn * v[t].x; ay += wn * v[t].y; az += wn * v[t].z; aw += wn * v[t].w;
        }
    }
    for (; j < e; j++) {
        int2 p = epack[j];
        float wn = __int_as_float(p.y);
        float4 v = ((const float4*)(H + (size_t)p.x * CH))[lane];
        ax += wn * v.x; ay += wn * v.y; az += wn * v.z; aw += wn * v.w;
    }
    float4 b = ((const float4*)bias)[lane];
    ax += b.x; ay += b.y; az += b.z; aw += b.w;
    if (do_gelu) {
        ax = gelu_f(ax); ay = gelu_f(ay); az = gelu_f(az); aw = gelu_f(aw);
    }
    ((float4*)(out + (size_t)node * CH))[lane] = make_float4(ax, ay, az, aw);
}

// ---------------- launcher ----------------

extern "C" void kernel_launch(void* const* d_in, const int* in_sizes, int n_in,
                              void* d_out, int out_size, void* d_ws, size_t ws_size,
                              hipStream_t stream) {
    const float* x  = (const float*)d_in[0];
    const void*  ei = d_in[1];
    const float* W1 = (const float*)d_in[3]; const float* b1 = (const float*)d_in[4];
    const float* W2 = (const float*)d_in[5]; const float* b2 = (const float*)d_in[6];
    const float* W3 = (const float*)d_in[7]; const float* b3 = (const float*)d_in[8];

    int N = in_sizes[0] / CH;
    int E = in_sizes[1] / 2;
    float* out = (float*)d_out;

    char* ws = (char*)d_ws;
    auto take = [&](size_t bytes) {
        char* p = ws;
        ws += (bytes + 15) & ~(size_t)15;
        return p;
    };
    float*    H      = (float*)   take((size_t)N * CH * sizeof(float));
    int*      deg    = (int*)     take((size_t)N * sizeof(int));
    float*    dis    = (float*)   take((size_t)N * sizeof(float));
    int*      rowptr = (int*)     take((size_t)(N + 1) * sizeof(int));
    int*      cnt    = (int*)     take((size_t)N * sizeof(int));
    int*      part   = (int*)     take(4096);
    int*      flag   = (int*)     take(16);
    int2*     epack  = (int2*)    take((size_t)E * sizeof(int2));
    _Float16* Wh1    = (_Float16*)take((size_t)CH * CH * 2);
    _Float16* Wl1    = (_Float16*)take((size_t)CH * CH * 2);
    _Float16* Wh2    = (_Float16*)take((size_t)CH * CH * 2);
    _Float16* Wl2    = (_Float16*)take((size_t)CH * CH * 2);
    _Float16* Wh3    = (_Float16*)take((size_t)CH * CH * 2);
    _Float16* Wl3    = (_Float16*)take((size_t)CH * CH * 2);

    hipMemsetAsync(deg, 0, (size_t)N * sizeof(int), stream);
    hipMemsetAsync(cnt, 0, (size_t)N * sizeof(int), stream);

    int eb = (E + 255) / 256;
    int nb = (N + 255) / 256;

    k_detect<<<1, 64, 0, stream>>>(ei, flag, E);
    k_deg<<<eb, 256, 0, stream>>>(ei, flag, deg, E);
    k_dis<<<nb, 256, 0, stream>>>(deg, dis, N);
    k_scan_block<<<nb, 256, 0, stream>>>(deg, rowptr, part, N);
    k_scan_partial<<<1, 256, 0, stream>>>(part, nb);
    k_add_off<<<nb, 256, 0, stream>>>(rowptr, part, N, E);
    k_scatter<<<eb, 256, 0, stream>>>(ei, flag, dis, rowptr, cnt, epack, E);

    k_split_w<<<CH, CH, 0, stream>>>(W1, Wh1, Wl1);
    k_split_w<<<CH, CH, 0, stream>>>(W2, Wh2, Wl2);
    k_split_w<<<CH, CH, 0, stream>>>(W3, Wh3, Wl3);

    dim3 ggrid((N + GM - 1) / GM, CH / GN);
    dim3 agrid((N + 3) / 4);
    dim3 ablock(64, 4);

    // layer 1
    k_gemm16<<<ggrid, 256, 0, stream>>>(x, Wh1, Wl1, H, N);
    k_agg<<<agrid, ablock, 0, stream>>>(H, dis, rowptr, epack, b1, out, N, 1);
    // layer 2
    k_gemm16<<<ggrid, 256, 0, stream>>>(out, Wh2, Wl2, H, N);
    k_agg<<<agrid, ablock, 0, stream>>>(H, dis, rowptr, epack, b2, out, N, 1);
    // layer 3 (no gelu)
    k_gemm16<<<ggrid, 256, 0, stream>>>(out, Wh3, Wl3, H, N);
    k_agg<<<agrid, ablock, 0, stream>>>(H, dis, rowptr, epack, b3, out, N, 0);
}

// Round 5
// 485.658 us; speedup vs baseline: 1.8772x; 1.2069x over previous
//
#include <hip/hip_runtime.h>
#include <cstdint>
#include <cstddef>

#define CH 256      // all layers are 256-channel

typedef _Float16 f16x8 __attribute__((ext_vector_type(8)));
typedef float f32x4 __attribute__((ext_vector_type(4)));

#define GLOB(x) ((const __attribute__((address_space(1))) void*)(x))
#define LDSP(x) ((__attribute__((address_space(3))) void*)(x))

// ---------------- helpers ----------------

__device__ __forceinline__ int ld_idx(const void* p, long long i, int w64) {
    if (w64) return (int)((const long long*)p)[i];
    return ((const int*)p)[i];
}

__device__ __forceinline__ float gelu_f(float x) {
    float x3 = x * x * x;
    float t = tanhf(0.7978845608028654f * (x + 0.044715f * x3));
    return 0.5f * x * (1.0f + t);
}

// ---------------- preprocessing ----------------

__global__ void k_detect(const void* __restrict__ ei, int* __restrict__ flag, int E) {
    int l = threadIdx.x;  // 0..63
    long long k = ((long long)l * (long long)(E - 1)) / 63;
    int w = ((const int*)ei)[2 * k + 1];
    unsigned long long vote = __ballot(w == 0);
    if (l == 0) *flag = (vote == ~0ULL) ? 1 : 0;
}

__global__ void k_deg(const void* __restrict__ ei, const int* __restrict__ flag,
                      int* __restrict__ deg, int E) {
    int e = blockIdx.x * blockDim.x + threadIdx.x;
    if (e >= E) return;
    int w64 = *flag;
    int d = ld_idx(ei, (long long)E + e, w64);
    atomicAdd(&deg[d], 1);
}

__global__ void k_dis(const int* __restrict__ deg, float* __restrict__ dis, int N) {
    int n = blockIdx.x * blockDim.x + threadIdx.x;
    if (n >= N) return;
    dis[n] = 1.0f / sqrtf((float)(deg[n] + 1));
}

__global__ void k_scan_block(const int* __restrict__ deg, int* __restrict__ rowptr,
                             int* __restrict__ partial, int N) {
    __shared__ int s[256];
    int gid = blockIdx.x * 256 + threadIdx.x;
    int v = (gid < N) ? deg[gid] : 0;
    s[threadIdx.x] = v;
    __syncthreads();
    for (int off = 1; off < 256; off <<= 1) {
        int t = (threadIdx.x >= off) ? s[threadIdx.x - off] : 0;
        __syncthreads();
        s[threadIdx.x] += t;
        __syncthreads();
    }
    if (gid < N) rowptr[gid] = s[threadIdx.x] - v;
    if (threadIdx.x == 255) partial[blockIdx.x] = s[255];
}

__global__ void k_scan_partial(int* __restrict__ partial, int nb) {
    __shared__ int s[256];
    int i = threadIdx.x;
    int v = (i < nb) ? partial[i] : 0;
    s[i] = v;
    __syncthreads();
    for (int off = 1; off < 256; off <<= 1) {
        int t = (i >= off) ? s[i - off] : 0;
        __syncthreads();
        s[i] += t;
        __syncthreads();
    }
    if (i < nb) partial[i] = s[i] - v;
}

__global__ void k_add_off(int* __restrict__ rowptr, const int* __restrict__ partial,
                          int N, int E) {
    int gid = blockIdx.x * 256 + threadIdx.x;
    if (gid < N) rowptr[gid] += partial[blockIdx.x];
    if (gid == 0) rowptr[N] = E;
}

__global__ void k_scatter(const void* __restrict__ ei, const int* __restrict__ flag,
                          const float* __restrict__ dis, const int* __restrict__ rowptr,
                          int* __restrict__ cnt, int2* __restrict__ epack, int E) {
    int e = blockIdx.x * blockDim.x + threadIdx.x;
    if (e >= E) return;
    int w64 = *flag;
    int s = ld_idx(ei, e, w64);
    int d = ld_idx(ei, (long long)E + e, w64);
    int pos = rowptr[d] + atomicAdd(&cnt[d], 1);
    epack[pos] = make_int2(s, __float_as_int(dis[s] * dis[d]));
}

// ---------------- weight split: W[k][c] fp32 -> Wt hi/lo fp16 [c][k] ----------------

__global__ void k_split_w(const float* __restrict__ W, _Float16* __restrict__ Wh,
                          _Float16* __restrict__ Wl) {
    int k = threadIdx.x;   // 0..255
    int c = blockIdx.x;    // 0..255
    float v = W[k * CH + c];
    _Float16 h = (_Float16)v;
    Wh[c * CH + k] = h;
    Wl[c * CH + k] = (_Float16)(v - (float)h);
}

// ---------------- fp16x2 split GEMM via MFMA, packed-24 output ----------------
// H24[M rows x 768 B] = pack24(A[M,256] @ W), W pre-split+transposed.
// Block: 128x128 output, 4 waves of 64x64, MFMA 16x16x32_f16, K-step 32.

#define GM 128
#define GN 128
#define GK 32

__global__ __launch_bounds__(256, 2)
void k_gemm16(const float* __restrict__ A, const _Float16* __restrict__ Bh,
              const _Float16* __restrict__ Bl, uint8_t* __restrict__ H24, int M) {
    __shared__ __align__(16) char smem[65536];
    float*    lA = (float*)smem;              // [2][128*32] fp32  = 32 KB
    _Float16* lB = (_Float16*)(smem + 32768); // [2][2][128*32] f16 = 32 KB

    const int tid  = threadIdx.x;
    const int lane = tid & 63;
    const int wid  = tid >> 6;
    const int m0   = blockIdx.x * GM;
    const int n0   = blockIdx.y * GN;
    const int wm   = wid >> 1, wn = wid & 1;
    const int r15  = lane & 15, kg = lane >> 4;

    // stage one K-step tile: A = 1024 chunks(16B), Bh = 512, Bl = 512 -> 32 calls, 8/wave
    auto stage = [&](int buf, int k0) {
        #pragma unroll
        for (int c = 0; c < 8; c++) {
            int call = wid * 8 + c;
            if (call < 16) {                        // A fp32: 128 rows x 8 chunks
                int L = call * 64 + lane;
                int row = L >> 3, ch = L & 7;
                int gr = m0 + row; gr = (gr < M) ? gr : (M - 1);
                const float* g = A + (size_t)gr * CH + k0 + ((ch ^ (row & 7)) << 2);
                __builtin_amdgcn_global_load_lds(GLOB(g), LDSP(&lA[buf * 4096 + call * 256]), 16, 0, 0);
            } else if (call < 24) {                 // B hi: 128 rows x 4 chunks
                int cc = call - 16;
                int L = cc * 64 + lane;
                int row = L >> 2, ch = L & 3;
                const _Float16* g = Bh + (size_t)(n0 + row) * CH + k0 + ((ch ^ ((row >> 1) & 3)) << 3);
                __builtin_amdgcn_global_load_lds(GLOB(g), LDSP(&lB[buf * 8192 + cc * 512]), 16, 0, 0);
            } else {                                // B lo
                int cc = call - 24;
                int L = cc * 64 + lane;
                int row = L >> 2, ch = L & 3;
                const _Float16* g = Bl + (size_t)(n0 + row) * CH + k0 + ((ch ^ ((row >> 1) & 3)) << 3);
                __builtin_amdgcn_global_load_lds(GLOB(g), LDSP(&lB[buf * 8192 + 4096 + cc * 512]), 16, 0, 0);
            }
        }
    };

    f32x4 acc[4][4];
    #pragma unroll
    for (int i = 0; i < 4; i++)
        #pragma unroll
        for (int n = 0; n < 4; n++)
            acc[i][n] = (f32x4){0.f, 0.f, 0.f, 0.f};

    stage(0, 0);
    __syncthreads();

    for (int ks = 0; ks < 8; ks++) {
        int cur = ks & 1;
        if (ks < 7) stage(cur ^ 1, (ks + 1) * GK);

        f16x8 ah[4], al[4], bh[4], bl[4];
        #pragma unroll
        for (int i = 0; i < 4; i++) {
            int R  = wm * 64 + i * 16 + r15;
            int p0 = (2 * kg) ^ (R & 7);
            const f32x4* base = (const f32x4*)&lA[cur * 4096 + R * GK];
            f32x4 va = base[p0];
            f32x4 vb = base[p0 ^ 1];
            #pragma unroll
            for (int j = 0; j < 4; j++) {
                float v = va[j];
                _Float16 h = (_Float16)v;
                ah[i][j] = h;
                al[i][j] = (_Float16)(v - (float)h);
            }
            #pragma unroll
            for (int j = 0; j < 4; j++) {
                float v = vb[j];
                _Float16 h = (_Float16)v;
                ah[i][4 + j] = h;
                al[i][4 + j] = (_Float16)(v - (float)h);
            }
        }
        #pragma unroll
        for (int n = 0; n < 4; n++) {
            int C = wn * 64 + n * 16 + r15;
            int p = kg ^ ((C >> 1) & 3);
            bh[n] = *(const f16x8*)&lB[cur * 8192 + C * GK + p * 8];
            bl[n] = *(const f16x8*)&lB[cur * 8192 + 4096 + C * GK + p * 8];
        }
        #pragma unroll
        for (int i = 0; i < 4; i++)
            #pragma unroll
            for (int n = 0; n < 4; n++) {
                acc[i][n] = __builtin_amdgcn_mfma_f32_16x16x32_f16(ah[i], bh[n], acc[i][n], 0, 0, 0);
                acc[i][n] = __builtin_amdgcn_mfma_f32_16x16x32_f16(ah[i], bl[n], acc[i][n], 0, 0, 0);
                acc[i][n] = __builtin_amdgcn_mfma_f32_16x16x32_f16(al[i], bh[n], acc[i][n], 0, 0, 0);
            }
        __syncthreads();
    }

    // ---- epilogue: transpose via LDS, pack 24-bit, 12B stores ----
    // Each wave owns a 16 KB region; C/D layout col=lane&15, row=(lane>>4)*4+reg.
    float* ep = (float*)smem + wid * 4096;   // 64x64 fp32 tile
    #pragma unroll
    for (int i = 0; i < 4; i++)
        #pragma unroll
        for (int n = 0; n < 4; n++)
            #pragma unroll
            for (int r = 0; r < 4; r++)
                ep[(i * 16 + kg * 4 + r) * 64 + n * 16 + r15] = acc[i][n][r];
    __syncthreads();

    int q = lane & 15;            // channel quad within tile
    int rsub = lane >> 4;         // row sub-index
    #pragma unroll
    for (int p = 0; p < 16; p++) {
        int lrow = p * 4 + rsub;                    // 0..63
        int grow = m0 + wm * 64 + lrow;
        if (grow < M) {
            unsigned u0 = __float_as_uint(ep[lrow * 64 + q * 4 + 0]);
            unsigned u1 = __float_as_uint(ep[lrow * 64 + q * 4 + 1]);
            unsigned u2 = __float_as_uint(ep[lrow * 64 + q * 4 + 2]);
            unsigned u3 = __float_as_uint(ep[lrow * 64 + q * 4 + 3]);
            unsigned t0 = (u0 + 0x80u) >> 8, t1 = (u1 + 0x80u) >> 8;
            unsigned t2 = (u2 + 0x80u) >> 8, t3 = (u3 + 0x80u) >> 8;
            uint3 d;
            d.x = t0 | (t1 << 24);
            d.y = (t1 >> 8) | (t2 << 16);
            d.z = (t2 >> 16) | (t3 << 8);
            int col = n0 + wn * 64 + q * 4;
            *(uint3*)(H24 + (size_t)grow * 768 + (size_t)col * 3) = d;
        }
    }
}

// ---------------- sparse aggregation (gather-CSR over packed-24 H) ----------------
// out[n] = dis[n]^2*h[n] + sum_e norm_e * h[src_e] (+bias, gelu?)
// one wave per node; lane handles 4 channels = 12 B packed

__device__ __forceinline__ void unpack24(uint3 v, float& f0, float& f1, float& f2, float& f3) {
    f0 = __uint_as_float(v.x << 8);
    f1 = __uint_as_float(((v.x >> 16) | (v.y << 16)) & 0xFFFFFF00u);
    f2 = __uint_as_float(((v.y >> 8) | (v.z << 24)) & 0xFFFFFF00u);
    f3 = __uint_as_float(v.z & 0xFFFFFF00u);
}

__global__ __launch_bounds__(256) void k_agg(const uint8_t* __restrict__ H24,
                                             const float* __restrict__ dis,
                                             const int* __restrict__ rowptr,
                                             const int2* __restrict__ epack,
                                             const float* __restrict__ bias,
                                             float* __restrict__ out, int N, int do_gelu) {
    int node = blockIdx.x * 4 + threadIdx.y;
    if (node >= N) return;
    int lane = threadIdx.x;  // 0..63
    float d = dis[node];
    float w = d * d;
    uint3 hv = *(const uint3*)(H24 + (size_t)node * 768 + (size_t)lane * 12);
    float h0, h1, h2, h3;
    unpack24(hv, h0, h1, h2, h3);
    float ax = w * h0, ay = w * h1, az = w * h2, aw = w * h3;
    int s = rowptr[node], e = rowptr[node + 1];
    int j = s;
    for (; j + 8 <= e; j += 8) {
        int2 p[8];
        #pragma unroll
        for (int t = 0; t < 8; t++) p[t] = epack[j + t];
        uint3 v[8];
        #pragma unroll
        for (int t = 0; t < 8; t++)
            v[t] = *(const uint3*)(H24 + (size_t)p[t].x * 768 + (size_t)lane * 12);
        #pragma unroll
        for (int t = 0; t < 8; t++) {
            float wn = __int_as_float(p[t].y);
            float f0, f1, f2, f3;
            unpack24(v[t], f0, f1, f2, f3);
            ax += wn * f0; ay += wn * f1; az += wn * f2; aw += wn * f3;
        }
    }
    for (; j < e; j++) {
        int2 p = epack[j];
        float wn = __int_as_float(p.y);
        uint3 v = *(const uint3*)(H24 + (size_t)p.x * 768 + (size_t)lane * 12);
        float f0, f1, f2, f3;
        unpack24(v, f0, f1, f2, f3);
        ax += wn * f0; ay += wn * f1; az += wn * f2; aw += wn * f3;
    }
    float4 b = ((const float4*)bias)[lane];
    ax += b.x; ay += b.y; az += b.z; aw += b.w;
    if (do_gelu) {
        ax = gelu_f(ax); ay = gelu_f(ay); az = gelu_f(az); aw = gelu_f(aw);
    }
    ((float4*)(out + (size_t)node * CH))[lane] = make_float4(ax, ay, az, aw);
}

// ---------------- launcher ----------------

extern "C" void kernel_launch(void* const* d_in, const int* in_sizes, int n_in,
                              void* d_out, int out_size, void* d_ws, size_t ws_size,
                              hipStream_t stream) {
    const float* x  = (const float*)d_in[0];
    const void*  ei = d_in[1];
    const float* W1 = (const float*)d_in[3]; const float* b1 = (const float*)d_in[4];
    const float* W2 = (const float*)d_in[5]; const float* b2 = (const float*)d_in[6];
    const float* W3 = (const float*)d_in[7]; const float* b3 = (const float*)d_in[8];

    int N = in_sizes[0] / CH;
    int E = in_sizes[1] / 2;
    float* out = (float*)d_out;

    char* ws = (char*)d_ws;
    auto take = [&](size_t bytes) {
        char* p = ws;
        ws += (bytes + 15) & ~(size_t)15;
        return p;
    };
    uint8_t*  H24    = (uint8_t*) take((size_t)N * 768);
    int*      deg    = (int*)     take((size_t)N * sizeof(int));
    float*    dis    = (float*)   take((size_t)N * sizeof(float));
    int*      rowptr = (int*)     take((size_t)(N + 1) * sizeof(int));
    int*      cnt    = (int*)     take((size_t)N * sizeof(int));
    int*      part   = (int*)     take(4096);
    int*      flag   = (int*)     take(16);
    int2*     epack  = (int2*)    take((size_t)E * sizeof(int2));
    _Float16* Wh1    = (_Float16*)take((size_t)CH * CH * 2);
    _Float16* Wl1    = (_Float16*)take((size_t)CH * CH * 2);
    _Float16* Wh2    = (_Float16*)take((size_t)CH * CH * 2);
    _Float16* Wl2    = (_Float16*)take((size_t)CH * CH * 2);
    _Float16* Wh3    = (_Float16*)take((size_t)CH * CH * 2);
    _Float16* Wl3    = (_Float16*)take((size_t)CH * CH * 2);

    hipMemsetAsync(deg, 0, (size_t)N * sizeof(int), stream);
    hipMemsetAsync(cnt, 0, (size_t)N * sizeof(int), stream);

    int eb = (E + 255) / 256;
    int nb = (N + 255) / 256;

    k_detect<<<1, 64, 0, stream>>>(ei, flag, E);
    k_deg<<<eb, 256, 0, stream>>>(ei, flag, deg, E);
    k_dis<<<nb, 256, 0, stream>>>(deg, dis, N);
    k_scan_block<<<nb, 256, 0, stream>>>(deg, rowptr, part, N);
    k_scan_partial<<<1, 256, 0, stream>>>(part, nb);
    k_add_off<<<nb, 256, 0, stream>>>(rowptr, part, N, E);
    k_scatter<<<eb, 256, 0, stream>>>(ei, flag, dis, rowptr, cnt, epack, E);

    k_split_w<<<CH, CH, 0, stream>>>(W1, Wh1, Wl1);
    k_split_w<<<CH, CH, 0, stream>>>(W2, Wh2, Wl2);
    k_split_w<<<CH, CH, 0, stream>>>(W3, Wh3, Wl3);

    dim3 ggrid((N + GM - 1) / GM, CH / GN);
    dim3 agrid((N + 3) / 4);
    dim3 ablock(64, 4);

    // layer 1
    k_gemm16<<<ggrid, 256, 0, stream>>>(x, Wh1, Wl1, H24, N);
    k_agg<<<agrid, ablock, 0, stream>>>(H24, dis, rowptr, epack, b1, out, N, 1);
    // layer 2
    k_gemm16<<<ggrid, 256, 0, stream>>>(out, Wh2, Wl2, H24, N);
    k_agg<<<agrid, ablock, 0, stream>>>(H24, dis, rowptr, epack, b2, out, N, 1);
    // layer 3 (no gelu)
    k_gemm16<<<ggrid, 256, 0, stream>>>(out, Wh3, Wl3, H24, N);
    k_agg<<<agrid, ablock, 0, stream>>>(H24, dis, rowptr, epack, b3, out, N, 0);
}

// Round 6
// 422.006 us; speedup vs baseline: 2.1603x; 1.1508x over previous
//
#include <hip/hip_runtime.h>
#include <cstdint>
#include <cstddef>

#define CH 256      // all layers are 256-channel

typedef _Float16 f16x8 __attribute__((ext_vector_type(8)));
typedef float f32x4 __attribute__((ext_vector_type(4)));

#define GLOB(x) ((const __attribute__((address_space(1))) void*)(x))
#define LDSP(x) ((__attribute__((address_space(3))) void*)(x))

// ---------------- helpers ----------------

__device__ __forceinline__ int ld_idx(const void* p, long long i, int w64) {
    if (w64) return (int)((const long long*)p)[i];
    return ((const int*)p)[i];
}

__device__ __forceinline__ float gelu_f(float x) {
    float x3 = x * x * x;
    float t = tanhf(0.7978845608028654f * (x + 0.044715f * x3));
    return 0.5f * x * (1.0f + t);
}

// ---------------- preprocessing ----------------

__global__ void k_detect(const void* __restrict__ ei, int* __restrict__ flag, int E) {
    int l = threadIdx.x;  // 0..63
    long long k = ((long long)l * (long long)(E - 1)) / 63;
    int w = ((const int*)ei)[2 * k + 1];
    unsigned long long vote = __ballot(w == 0);
    if (l == 0) *flag = (vote == ~0ULL) ? 1 : 0;
}

__global__ void k_deg(const void* __restrict__ ei, const int* __restrict__ flag,
                      int* __restrict__ deg, int E) {
    int e = blockIdx.x * blockDim.x + threadIdx.x;
    if (e >= E) return;
    int w64 = *flag;
    int d = ld_idx(ei, (long long)E + e, w64);
    atomicAdd(&deg[d], 1);
}

__global__ void k_dis(const int* __restrict__ deg, float* __restrict__ dis, int N) {
    int n = blockIdx.x * blockDim.x + threadIdx.x;
    if (n >= N) return;
    dis[n] = 1.0f / sqrtf((float)(deg[n] + 1));
}

__global__ void k_scan_block(const int* __restrict__ deg, int* __restrict__ rowptr,
                             int* __restrict__ partial, int N) {
    __shared__ int s[256];
    int gid = blockIdx.x * 256 + threadIdx.x;
    int v = (gid < N) ? deg[gid] : 0;
    s[threadIdx.x] = v;
    __syncthreads();
    for (int off = 1; off < 256; off <<= 1) {
        int t = (threadIdx.x >= off) ? s[threadIdx.x - off] : 0;
        __syncthreads();
        s[threadIdx.x] += t;
        __syncthreads();
    }
    if (gid < N) rowptr[gid] = s[threadIdx.x] - v;
    if (threadIdx.x == 255) partial[blockIdx.x] = s[255];
}

__global__ void k_scan_partial(int* __restrict__ partial, int nb) {
    __shared__ int s[256];
    int i = threadIdx.x;
    int v = (i < nb) ? partial[i] : 0;
    s[i] = v;
    __syncthreads();
    for (int off = 1; off < 256; off <<= 1) {
        int t = (i >= off) ? s[i - off] : 0;
        __syncthreads();
        s[i] += t;
        __syncthreads();
    }
    if (i < nb) partial[i] = s[i] - v;
}

__global__ void k_add_off(int* __restrict__ rowptr, const int* __restrict__ partial,
                          int N, int E) {
    int gid = blockIdx.x * 256 + threadIdx.x;
    if (gid < N) rowptr[gid] += partial[blockIdx.x];
    if (gid == 0) rowptr[N] = E;
}

__global__ void k_scatter(const void* __restrict__ ei, const int* __restrict__ flag,
                          const float* __restrict__ dis, const int* __restrict__ rowptr,
                          int* __restrict__ cnt, int2* __restrict__ epack, int E) {
    int e = blockIdx.x * blockDim.x + threadIdx.x;
    if (e >= E) return;
    int w64 = *flag;
    int s = ld_idx(ei, e, w64);
    int d = ld_idx(ei, (long long)E + e, w64);
    int pos = rowptr[d] + atomicAdd(&cnt[d], 1);
    epack[pos] = make_int2(s, __float_as_int(dis[s] * dis[d]));
}

// ---------------- weight split: W[k][c] fp32 -> Wt hi/lo fp16 [c][k] ----------------

__global__ void k_split_w(const float* __restrict__ W, _Float16* __restrict__ Wh,
                          _Float16* __restrict__ Wl) {
    int k = threadIdx.x;   // 0..255
    int c = blockIdx.x;    // 0..255
    float v = W[k * CH + c];
    _Float16 h = (_Float16)v;
    Wh[c * CH + k] = h;
    Wl[c * CH + k] = (_Float16)(v - (float)h);
}

// ---------------- fp16x2 split GEMM via MFMA, int16-quantized output ----------------
// H16[M rows x 512 B] = quant16(A[M,256] @ W), per-(tile,half) scale in scales[node*2+half].
// Block: 128x128 output, 4 waves of 64x64, MFMA 16x16x32_f16, K-step 32.

#define GM 128
#define GN 128
#define GK 32

__global__ __launch_bounds__(256, 2)
void k_gemm16(const float* __restrict__ A, const _Float16* __restrict__ Bh,
              const _Float16* __restrict__ Bl, uint8_t* __restrict__ H16,
              float* __restrict__ scales, int M) {
    __shared__ __align__(16) char smem[65536];
    float*    lA = (float*)smem;              // [2][128*32] fp32  = 32 KB
    _Float16* lB = (_Float16*)(smem + 32768); // [2][2][128*32] f16 = 32 KB

    const int tid  = threadIdx.x;
    const int lane = tid & 63;
    const int wid  = tid >> 6;
    const int m0   = blockIdx.x * GM;
    const int n0   = blockIdx.y * GN;
    const int wm   = wid >> 1, wn = wid & 1;
    const int r15  = lane & 15, kg = lane >> 4;

    // stage one K-step tile: A = 1024 chunks(16B), Bh = 512, Bl = 512 -> 32 calls, 8/wave
    auto stage = [&](int buf, int k0) {
        #pragma unroll
        for (int c = 0; c < 8; c++) {
            int call = wid * 8 + c;
            if (call < 16) {                        // A fp32: 128 rows x 8 chunks
                int L = call * 64 + lane;
                int row = L >> 3, ch = L & 7;
                int gr = m0 + row; gr = (gr < M) ? gr : (M - 1);
                const float* g = A + (size_t)gr * CH + k0 + ((ch ^ (row & 7)) << 2);
                __builtin_amdgcn_global_load_lds(GLOB(g), LDSP(&lA[buf * 4096 + call * 256]), 16, 0, 0);
            } else if (call < 24) {                 // B hi: 128 rows x 4 chunks
                int cc = call - 16;
                int L = cc * 64 + lane;
                int row = L >> 2, ch = L & 3;
                const _Float16* g = Bh + (size_t)(n0 + row) * CH + k0 + ((ch ^ ((row >> 1) & 3)) << 3);
                __builtin_amdgcn_global_load_lds(GLOB(g), LDSP(&lB[buf * 8192 + cc * 512]), 16, 0, 0);
            } else {                                // B lo
                int cc = call - 24;
                int L = cc * 64 + lane;
                int row = L >> 2, ch = L & 3;
                const _Float16* g = Bl + (size_t)(n0 + row) * CH + k0 + ((ch ^ ((row >> 1) & 3)) << 3);
                __builtin_amdgcn_global_load_lds(GLOB(g), LDSP(&lB[buf * 8192 + 4096 + cc * 512]), 16, 0, 0);
            }
        }
    };

    f32x4 acc[4][4];
    #pragma unroll
    for (int i = 0; i < 4; i++)
        #pragma unroll
        for (int n = 0; n < 4; n++)
            acc[i][n] = (f32x4){0.f, 0.f, 0.f, 0.f};

    stage(0, 0);
    __syncthreads();

    for (int ks = 0; ks < 8; ks++) {
        int cur = ks & 1;
        if (ks < 7) stage(cur ^ 1, (ks + 1) * GK);

        f16x8 ah[4], al[4], bh[4], bl[4];
        #pragma unroll
        for (int i = 0; i < 4; i++) {
            int R  = wm * 64 + i * 16 + r15;
            int p0 = (2 * kg) ^ (R & 7);
            const f32x4* base = (const f32x4*)&lA[cur * 4096 + R * GK];
            f32x4 va = base[p0];
            f32x4 vb = base[p0 ^ 1];
            #pragma unroll
            for (int j = 0; j < 4; j++) {
                float v = va[j];
                _Float16 h = (_Float16)v;
                ah[i][j] = h;
                al[i][j] = (_Float16)(v - (float)h);
            }
            #pragma unroll
            for (int j = 0; j < 4; j++) {
                float v = vb[j];
                _Float16 h = (_Float16)v;
                ah[i][4 + j] = h;
                al[i][4 + j] = (_Float16)(v - (float)h);
            }
        }
        #pragma unroll
        for (int n = 0; n < 4; n++) {
            int C = wn * 64 + n * 16 + r15;
            int p = kg ^ ((C >> 1) & 3);
            bh[n] = *(const f16x8*)&lB[cur * 8192 + C * GK + p * 8];
            bl[n] = *(const f16x8*)&lB[cur * 8192 + 4096 + C * GK + p * 8];
        }
        #pragma unroll
        for (int i = 0; i < 4; i++)
            #pragma unroll
            for (int n = 0; n < 4; n++) {
                acc[i][n] = __builtin_amdgcn_mfma_f32_16x16x32_f16(ah[i], bh[n], acc[i][n], 0, 0, 0);
                acc[i][n] = __builtin_amdgcn_mfma_f32_16x16x32_f16(ah[i], bl[n], acc[i][n], 0, 0, 0);
                acc[i][n] = __builtin_amdgcn_mfma_f32_16x16x32_f16(al[i], bh[n], acc[i][n], 0, 0, 0);
            }
        __syncthreads();
    }

    // ---- epilogue: tile absmax -> scale, transpose via LDS, int16 store ----
    // 1) tile max from registers
    float mx = 0.f;
    #pragma unroll
    for (int i = 0; i < 4; i++)
        #pragma unroll
        for (int n = 0; n < 4; n++)
            #pragma unroll
            for (int r = 0; r < 4; r++)
                mx = fmaxf(mx, fabsf(acc[i][n][r]));
    #pragma unroll
    for (int off = 32; off > 0; off >>= 1)
        mx = fmaxf(mx, __shfl_xor(mx, off));
    if (lane == 0) ((float*)smem)[wid] = mx;
    __syncthreads();
    float tmax = fmaxf(fmaxf(((float*)smem)[0], ((float*)smem)[1]),
                       fmaxf(((float*)smem)[2], ((float*)smem)[3]));
    float scl = tmax * (1.0f / 32767.0f);
    float inv = (tmax > 0.f) ? (32767.0f / tmax) : 0.f;
    __syncthreads();

    // 2) transpose: each wave owns a 16 KB region; C/D layout col=lane&15, row=(lane>>4)*4+reg
    float* ep = (float*)smem + wid * 4096;   // 64x64 fp32 tile
    #pragma unroll
    for (int i = 0; i < 4; i++)
        #pragma unroll
        for (int n = 0; n < 4; n++)
            #pragma unroll
            for (int r = 0; r < 4; r++)
                ep[(i * 16 + kg * 4 + r) * 64 + n * 16 + r15] = acc[i][n][r];
    __syncthreads();

    // 3) quantize + store 8 B per lane-row
    int q = lane & 15;            // channel quad within tile
    int rsub = lane >> 4;         // row sub-index
    #pragma unroll
    for (int p = 0; p < 16; p++) {
        int lrow = p * 4 + rsub;                    // 0..63
        int grow = m0 + wm * 64 + lrow;
        if (grow < M) {
            int q0 = __float2int_rn(ep[lrow * 64 + q * 4 + 0] * inv);
            int q1 = __float2int_rn(ep[lrow * 64 + q * 4 + 1] * inv);
            int q2 = __float2int_rn(ep[lrow * 64 + q * 4 + 2] * inv);
            int q3 = __float2int_rn(ep[lrow * 64 + q * 4 + 3] * inv);
            uint2 d;
            d.x = (q0 & 0xFFFF) | (q1 << 16);
            d.y = (q2 & 0xFFFF) | (q3 << 16);
            int col = n0 + wn * 64 + q * 4;
            *(uint2*)(H16 + (size_t)grow * 512 + (size_t)col * 2) = d;
        }
    }

    // 4) scales (duplicated per row for simple agg-side lookup)
    if (tid < GM && m0 + tid < M) scales[(size_t)(m0 + tid) * 2 + (n0 >> 7)] = scl;
}

// ---------------- sparse aggregation (gather-CSR over int16 H) ----------------
// out[n] = dis[n]^2*h[n] + sum_e norm_e * h[src_e] (+bias, gelu?)
// one wave per node; lane handles 4 channels = 8 B quantized

__global__ __launch_bounds__(256) void k_agg(const uint8_t* __restrict__ H16,
                                             const float* __restrict__ scales,
                                             const float* __restrict__ dis,
                                             const int* __restrict__ rowptr,
                                             const int2* __restrict__ epack,
                                             const float* __restrict__ bias,
                                             float* __restrict__ out, int N, int do_gelu) {
    int node = blockIdx.x * 4 + threadIdx.y;
    if (node >= N) return;
    int lane = threadIdx.x;  // 0..63
    int half = lane >> 5;    // which 128-ch half this lane's 4 channels live in
    float d = dis[node];
    short4 hv = *(const short4*)(H16 + (size_t)node * 512 + (size_t)lane * 8);
    float wself = d * d * scales[(size_t)node * 2 + half];
    float ax = wself * (float)hv.x, ay = wself * (float)hv.y;
    float az = wself * (float)hv.z, aw = wself * (float)hv.w;
    int s = rowptr[node], e = rowptr[node + 1];
    int j = s;
    for (; j + 8 <= e; j += 8) {
        int2 p[8];
        #pragma unroll
        for (int t = 0; t < 8; t++) p[t] = epack[j + t];
        short4 v[8];
        float sc[8];
        #pragma unroll
        for (int t = 0; t < 8; t++) {
            v[t] = *(const short4*)(H16 + (size_t)p[t].x * 512 + (size_t)lane * 8);
            sc[t] = scales[(size_t)p[t].x * 2 + half];
        }
        #pragma unroll
        for (int t = 0; t < 8; t++) {
            float wn = __int_as_float(p[t].y) * sc[t];
            ax += wn * (float)v[t].x; ay += wn * (float)v[t].y;
            az += wn * (float)v[t].z; aw += wn * (float)v[t].w;
        }
    }
    for (; j < e; j++) {
        int2 p = epack[j];
        float wn = __int_as_float(p.y) * scales[(size_t)p.x * 2 + half];
        short4 v = *(const short4*)(H16 + (size_t)p.x * 512 + (size_t)lane * 8);
        ax += wn * (float)v.x; ay += wn * (float)v.y;
        az += wn * (float)v.z; aw += wn * (float)v.w;
    }
    float4 b = ((const float4*)bias)[lane];
    ax += b.x; ay += b.y; az += b.z; aw += b.w;
    if (do_gelu) {
        ax = gelu_f(ax); ay = gelu_f(ay); az = gelu_f(az); aw = gelu_f(aw);
    }
    ((float4*)(out + (size_t)node * CH))[lane] = make_float4(ax, ay, az, aw);
}

// ---------------- launcher ----------------

extern "C" void kernel_launch(void* const* d_in, const int* in_sizes, int n_in,
                              void* d_out, int out_size, void* d_ws, size_t ws_size,
                              hipStream_t stream) {
    const float* x  = (const float*)d_in[0];
    const void*  ei = d_in[1];
    const float* W1 = (const float*)d_in[3]; const float* b1 = (const float*)d_in[4];
    const float* W2 = (const float*)d_in[5]; const float* b2 = (const float*)d_in[6];
    const float* W3 = (const float*)d_in[7]; const float* b3 = (const float*)d_in[8];

    int N = in_sizes[0] / CH;
    int E = in_sizes[1] / 2;
    float* out = (float*)d_out;

    char* ws = (char*)d_ws;
    auto take = [&](size_t bytes) {
        char* p = ws;
        ws += (bytes + 15) & ~(size_t)15;
        return p;
    };
    uint8_t*  H16    = (uint8_t*) take((size_t)N * 512);
    float*    scales = (float*)   take((size_t)N * 2 * sizeof(float));
    int*      deg    = (int*)     take((size_t)N * sizeof(int));
    float*    dis    = (float*)   take((size_t)N * sizeof(float));
    int*      rowptr = (int*)     take((size_t)(N + 1) * sizeof(int));
    int*      cnt    = (int*)     take((size_t)N * sizeof(int));
    int*      part   = (int*)     take(4096);
    int*      flag   = (int*)     take(16);
    int2*     epack  = (int2*)    take((size_t)E * sizeof(int2));
    _Float16* Wh1    = (_Float16*)take((size_t)CH * CH * 2);
    _Float16* Wl1    = (_Float16*)take((size_t)CH * CH * 2);
    _Float16* Wh2    = (_Float16*)take((size_t)CH * CH * 2);
    _Float16* Wl2    = (_Float16*)take((size_t)CH * CH * 2);
    _Float16* Wh3    = (_Float16*)take((size_t)CH * CH * 2);
    _Float16* Wl3    = (_Float16*)take((size_t)CH * CH * 2);

    hipMemsetAsync(deg, 0, (size_t)N * sizeof(int), stream);
    hipMemsetAsync(cnt, 0, (size_t)N * sizeof(int), stream);

    int eb = (E + 255) / 256;
    int nb = (N + 255) / 256;

    k_detect<<<1, 64, 0, stream>>>(ei, flag, E);
    k_deg<<<eb, 256, 0, stream>>>(ei, flag, deg, E);
    k_dis<<<nb, 256, 0, stream>>>(deg, dis, N);
    k_scan_block<<<nb, 256, 0, stream>>>(deg, rowptr, part, N);
    k_scan_partial<<<1, 256, 0, stream>>>(part, nb);
    k_add_off<<<nb, 256, 0, stream>>>(rowptr, part, N, E);
    k_scatter<<<eb, 256, 0, stream>>>(ei, flag, dis, rowptr, cnt, epack, E);

    k_split_w<<<CH, CH, 0, stream>>>(W1, Wh1, Wl1);
    k_split_w<<<CH, CH, 0, stream>>>(W2, Wh2, Wl2);
    k_split_w<<<CH, CH, 0, stream>>>(W3, Wh3, Wl3);

    dim3 ggrid((N + GM - 1) / GM, CH / GN);
    dim3 agrid((N + 3) / 4);
    dim3 ablock(64, 4);

    // layer 1
    k_gemm16<<<ggrid, 256, 0, stream>>>(x, Wh1, Wl1, H16, scales, N);
    k_agg<<<agrid, ablock, 0, stream>>>(H16, scales, dis, rowptr, epack, b1, out, N, 1);
    // layer 2
    k_gemm16<<<ggrid, 256, 0, stream>>>(out, Wh2, Wl2, H16, scales, N);
    k_agg<<<agrid, ablock, 0, stream>>>(H16, scales, dis, rowptr, epack, b2, out, N, 1);
    // layer 3 (no gelu)
    k_gemm16<<<ggrid, 256, 0, stream>>>(out, Wh3, Wl3, H16, scales, N);
    k_agg<<<agrid, ablock, 0, stream>>>(H16, scales, dis, rowptr, epack, b3, out, N, 0);
}